// Round 8
// baseline (253.124 us; speedup 1.0000x reference)
//
#include <hip/hip_runtime.h>
#include <math.h>

typedef _Float16 f16;
typedef _Float16 f16x4 __attribute__((ext_vector_type(4)));
typedef _Float16 f16x8 __attribute__((ext_vector_type(8)));
typedef float f32x4 __attribute__((ext_vector_type(4)));
typedef float f32x8 __attribute__((ext_vector_type(8)));

#define AS1 __attribute__((address_space(1)))
#define AS3 __attribute__((address_space(3)))

__device__ __forceinline__ void gld_lds16(const f16* g, f16* l) {
#if defined(__has_builtin) && __has_builtin(__builtin_amdgcn_global_load_lds)
    __builtin_amdgcn_global_load_lds((const AS1 void*)g, (AS3 void*)l, 16, 0, 0);
#else
    *(uint4*)l = *(const uint4*)g;
#endif
}

// ---------------- fused pre-pass: transpose_input U permute_w U permute_rw U zero-s0 ----
// blockIdx ranges: [0,13312) transpose (128x8x13), [13312,13568) permute_w (256),
// [13568,15008) permute_rw (1440), [15008,15028) zero s0 (20).
__global__ __launch_bounds__(256) void mega_pre(
    const float* __restrict__ inp, f16* __restrict__ in_t,
    const float* __restrict__ cw,  f16* __restrict__ w_t,
    const float* __restrict__ rw,  f16* __restrict__ rwh,
    float* __restrict__ s0)
{
    __shared__ __align__(16) char smem[81 * 258 * 2];
    const int bx = blockIdx.x, tid = threadIdx.x;

    if (bx < 13312) {
        // ---- transpose_input: [128,256,20,20] f32 -> [128,20,20,256] f16 ----
        const int b = bx & 127, c0 = ((bx >> 7) & 7) * 32, p0 = (bx >> 10) * 32;
        const int tx = tid & 31, ty = tid >> 5;            // 32 x 8
        float (*t)[33] = (float(*)[33])smem;
#pragma unroll
        for (int j = 0; j < 4; ++j) {
            int c = ty + j * 8, p = p0 + tx;
            if (p < 400) t[c][tx] = inp[((size_t)b * 256 + c0 + c) * 400 + p];
        }
        __syncthreads();
#pragma unroll
        for (int j = 0; j < 4; ++j) {
            int p = p0 + ty + j * 8;
            if (p < 400) in_t[((size_t)b * 400 + p) * 256 + c0 + tx] = (f16)t[tx][ty + j * 8];
        }
    } else if (bx < 13568) {
        // ---- permute_w: [256][256][81] f32 -> w_t[n][p*256+cin] f16 ----
        const int n = bx - 13312;
        f16* buf = (f16*)smem;
        const float* src = cw + (size_t)n * 20736;
        for (int i = tid; i < 20736; i += 256) {
            int cin = i / 81, p = i - cin * 81;
            buf[p * 258 + cin] = (f16)src[i];
        }
        __syncthreads();
        f16* dst = w_t + (size_t)n * 20736;
        for (int j = tid; j < 20736; j += 256) {
            int p = j >> 8, cin = j & 255;
            dst[j] = buf[p * 258 + cin];
        }
    } else if (bx < 15008) {
        // ---- permute_rw: rw [10,1152,8,16] f32 -> rwh [10,1152,16,8] f16 ----
        int g = (bx - 13568) * 256 + tid;                  // over 368640
        int cr = g >> 5, rem = g & 31;
        int o = rem >> 1, h = (rem & 1) * 4;
        const float* src = rw + (size_t)cr * 128 + o;
        f16x4 v;
#pragma unroll
        for (int j = 0; j < 4; ++j) v[j] = (f16)src[(h + j) * 16];
        *(f16x4*)(rwh + (size_t)cr * 128 + o * 8 + h) = v;
    } else {
        // ---- zero s0: 20480 floats = 5120 float4 ----
        int idx = (bx - 15008) * 256 + tid;
        ((float4*)s0)[idx] = make_float4(0.f, 0.f, 0.f, 0.f);
    }
}

// ---------------- conv as implicit-im2col MFMA GEMM, 2-phase interleaved pipeline ------
// (UNCHANGED — measured ~61 us, MfmaUtil ~33.)
#define SPLITK 14
__global__ __launch_bounds__(256, 2) void conv_mfma(
    const f16* __restrict__ in_t,   // [128,20,20,256]
    const f16* __restrict__ w_t,    // [256,20736]
    f16* __restrict__ part)         // [14,4608,256] f16
{
    __shared__ f16 As[3][128 * 32];
    __shared__ f16 Bs[3][256 * 32];
    const int tid = threadIdx.x;
    const int lane = tid & 63, wave = tid >> 6;
    const int wm = wave >> 1, wn = wave & 1;

    const int bid = blockIdx.x + 36 * blockIdx.z;
    const int wgid = (bid & 7) * 63 + (bid >> 3);
    const int m0 = (wgid % 36) * 128;
    const int kz = wgid / 36;

    const int kc0 = kz * 46 + (kz < 4 ? kz : 4);
    const int NT  = (kz < 4) ? 47 : 46;

    int srcA[2], srcB[4];
#pragma unroll
    for (int i = 0; i < 2; ++i) {
        int pairp = i * 32 + (tid >> 3);
        int chunk8 = (tid & 7) ^ (pairp & 7);
        int e = chunk8 >> 2, q4 = chunk8 & 3;
        int m = m0 + pairp * 2 + e;
        int b = m / 36, hw = m - b * 36;
        int ho = hw / 6, wo = hw - ho * 6;
        srcA[i] = ((b * 20 + 2 * ho) * 20 + 2 * wo) * 256 + q4 * 8;
    }
#pragma unroll
    for (int i = 0; i < 4; ++i) {
        int pairp = i * 32 + (tid >> 3);
        int chunk8 = (tid & 7) ^ (pairp & 7);
        int e = chunk8 >> 2, q4 = chunk8 & 3;
        int n = pairp * 2 + e;
        srcB[i] = n * 20736 + q4 * 8;
    }

    const int row = lane & 15, quad = lane >> 4;
    int offA[4], offB[8];
#pragma unroll
    for (int mt = 0; mt < 4; ++mt) {
        int m = wm * 64 + mt * 16 + row;
        int ph8 = (((m & 1) << 2) + quad) ^ ((m >> 1) & 7);
        offA[mt] = (m >> 1) * 64 + ph8 * 8;
    }
#pragma unroll
    for (int nt = 0; nt < 8; ++nt) {
        int n = wn * 128 + nt * 16 + row;
        int ph8 = (((n & 1) << 2) + quad) ^ ((n >> 1) & 7);
        offB[nt] = (n >> 1) * 64 + ph8 * 8;
    }

    f32x4 acc[4][8] = {};

#define KOFFS(T) int kc = kc0 + (T); int pp = kc >> 3, cq = kc & 7;           \
    int kh = pp / 9, kw = pp - kh * 9;                                        \
    int koffA = (kh * 20 + kw) * 256 + cq * 32; int koffB = kc * 32;
#define STAGE1(T, BUF) do { KOFFS(T)                                          \
        gld_lds16(in_t + srcA[0] + koffA, &As[BUF][tid * 8]);                 \
        gld_lds16(in_t + srcA[1] + koffA, &As[BUF][2048 + tid * 8]);          \
        gld_lds16(w_t + srcB[0] + koffB, &Bs[BUF][tid * 8]);                  \
    } while (0)
#define STAGE2(T, BUF) do { KOFFS(T)                                          \
        gld_lds16(w_t + srcB[1] + koffB, &Bs[BUF][2048 + tid * 8]);           \
        gld_lds16(w_t + srcB[2] + koffB, &Bs[BUF][4096 + tid * 8]);           \
        gld_lds16(w_t + srcB[3] + koffB, &Bs[BUF][6144 + tid * 8]);           \
    } while (0)

    STAGE1(0, 0); STAGE2(0, 0);
    STAGE1(1, 1); STAGE2(1, 1);
    asm volatile("s_waitcnt vmcnt(6)" ::: "memory");
    __builtin_amdgcn_s_barrier();

    int buf = 0;
    for (int t = 0; t < NT; ++t) {
        const f16* Ab = &As[buf][0];
        const f16* Bb = &Bs[buf][0];
        int bn = buf + 2; if (bn >= 3) bn -= 3;
        f16x8 af[4], bfr[8];

        // ---------------- phase A: af[0..3], bfr[0..3] -> acc[*][0..3] ----------------
#pragma unroll
        for (int mt = 0; mt < 4; ++mt) af[mt] = *(const f16x8*)(Ab + offA[mt]);
#pragma unroll
        for (int nt = 0; nt < 4; ++nt) bfr[nt] = *(const f16x8*)(Bb + offB[nt]);
        if (t + 2 < NT) STAGE1(t + 2, bn);
        __builtin_amdgcn_s_barrier();
        asm volatile("s_waitcnt lgkmcnt(0)" ::: "memory");
        __builtin_amdgcn_sched_barrier(0);
        __builtin_amdgcn_s_setprio(1);
#pragma unroll
        for (int mt = 0; mt < 4; ++mt)
#pragma unroll
            for (int nt = 0; nt < 4; ++nt)
                acc[mt][nt] = __builtin_amdgcn_mfma_f32_16x16x32_f16(
                    af[mt], bfr[nt], acc[mt][nt], 0, 0, 0);
        __builtin_amdgcn_s_setprio(0);
        __builtin_amdgcn_s_barrier();

        // ---------------- phase B: bfr[4..7] -> acc[*][4..7] --------------------------
#pragma unroll
        for (int nt = 4; nt < 8; ++nt) bfr[nt] = *(const f16x8*)(Bb + offB[nt]);
        if (t + 2 < NT) STAGE2(t + 2, bn);
        if (t + 2 < NT)
            asm volatile("s_waitcnt vmcnt(6)" ::: "memory");
        else if (t + 1 < NT)
            asm volatile("s_waitcnt vmcnt(0)" ::: "memory");
        __builtin_amdgcn_s_barrier();
        asm volatile("s_waitcnt lgkmcnt(0)" ::: "memory");
        __builtin_amdgcn_sched_barrier(0);
        __builtin_amdgcn_s_setprio(1);
#pragma unroll
        for (int mt = 0; mt < 4; ++mt)
#pragma unroll
            for (int nt = 4; nt < 8; ++nt)
                acc[mt][nt] = __builtin_amdgcn_mfma_f32_16x16x32_f16(
                    af[mt], bfr[nt], acc[mt][nt], 0, 0, 0);
        __builtin_amdgcn_s_setprio(0);
        __builtin_amdgcn_s_barrier();

        if (++buf == 3) buf = 0;
    }
#undef STAGE1
#undef STAGE2
#undef KOFFS

    const int col = lane & 15, qr = (lane >> 4) * 4;
    f16* pb = part + (size_t)kz * 4608 * 256;
#pragma unroll
    for (int mt = 0; mt < 4; ++mt)
#pragma unroll
        for (int rg = 0; rg < 4; ++rg) {
            int m = m0 + wm * 64 + mt * 16 + qr + rg;
#pragma unroll
            for (int nt = 0; nt < 8; ++nt) {
                int n = wn * 128 + nt * 16 + col;
                pb[(size_t)m * 256 + n] = (f16)acc[mt][nt][rg];
            }
        }
}

// ---------------- split-K reduce + bias + squash -> xh f16, 4-way split-s --------------
// Work item (m, g, si): si covers splits {0-3},{4-7},{8-11},{12-13}; si partials reduced
// via shfl_xor (si = tid bits 3..4, wave-local); si==0 lane does bias+squash+store.
// Grid 576 blocks (2.25/CU) — was 144 (0.56/CU, half the GPU idle).
__global__ __launch_bounds__(256) void combine_squash4(
    const f16* __restrict__ part, const float* __restrict__ bias,
    f16* __restrict__ xh)
{
    int idx = blockIdx.x * 256 + threadIdx.x;   // over 4608*8*4
    int g = idx & 7, si = (idx >> 3) & 3, m = idx >> 5;
    int b = m / 36, hw = m - b * 36;
    int sbeg = si * 4, scnt = (si < 3) ? 4 : 2;   // 4+4+4+2 = 14

    float val[8][4] = {};
    for (int s2 = 0; s2 < scnt; ++s2) {
        const f16* p = part + ((size_t)(sbeg + s2) * 4608 + m) * 256 + g * 4;
#pragma unroll
        for (int k = 0; k < 8; ++k) {
            f16x4 v = *(const f16x4*)(p + k * 32);
#pragma unroll
            for (int j = 0; j < 4; ++j) val[k][j] += (float)v[j];
        }
    }
    // reduce the 4 si-partials (tid bits 3,4 -> xor 8, 16: same wave)
#pragma unroll
    for (int k = 0; k < 8; ++k)
#pragma unroll
        for (int j = 0; j < 4; ++j) {
            val[k][j] += __shfl_xor(val[k][j], 8);
            val[k][j] += __shfl_xor(val[k][j], 16);
        }
    if (si == 0) {
#pragma unroll
        for (int j = 0; j < 4; ++j) {
            float sn = 0.f;
            float vb[8];
#pragma unroll
            for (int k = 0; k < 8; ++k) {
                vb[k] = val[k][j] + bias[k * 32 + g * 4 + j];
                sn += vb[k] * vb[k];
            }
            float scale = sqrtf(sn) / (1.f + sn);
            int r = (g * 4 + j) * 36 + hw;
            f16x8 hv;
#pragma unroll
            for (int k = 0; k < 8; ++k) hv[k] = (f16)(vb[k] * scale);
            *(f16x8*)(xh + ((size_t)b * 1152 + r) * 8) = hv;
        }
    }
}

// ---------------- pred (f16, materialized) + fused routing-iter-0 s-accumulation --------
// pred[c,b,r,o] = sum_k xh[b,r,k]*rwh[c,r,o,k]; s0[c,b,o] += sum_r pred. s0 pre-zeroed.
// R8: bb-loop unrolled x2, all 4 x-loads issued before compute (ILP over L2 latency).
__global__ __launch_bounds__(256) void pred_s0h(
    const f16* __restrict__ xh,     // [128,1152,8]
    const f16* __restrict__ rwh,    // [10,1152,16,8]
    f16* __restrict__ pred,         // [10,128,1152,16]
    float* __restrict__ s0)         // [10,128,16] pre-zeroed
{
    const int c = blockIdx.x, r0 = blockIdx.y * 32, b0 = blockIdx.z * 32;
    const int tid = threadIdx.x;
    const int o = tid & 15, rp = tid >> 4;
    const int r = r0 + rp * 2;

    __shared__ float s_sh[32 * 16];
    s_sh[tid] = 0.f; s_sh[tid + 256] = 0.f;

    f16x8 w0h = *(const f16x8*)(rwh + ((size_t)(c * 1152 + r) * 16 + o) * 8);
    f16x8 w1h = *(const f16x8*)(rwh + ((size_t)(c * 1152 + r + 1) * 16 + o) * 8);
    f32x8 W0 = __builtin_convertvector(w0h, f32x8);
    f32x8 W1 = __builtin_convertvector(w1h, f32x8);
    __syncthreads();

    for (int bb = 0; bb < 32; bb += 2) {
        const int ba = b0 + bb, bc = b0 + bb + 1;
        // issue all 4 loads before any compute
        f16x8 xa0 = *(const f16x8*)(xh + ((size_t)ba * 1152 + r) * 8);
        f16x8 xa1 = *(const f16x8*)(xh + ((size_t)ba * 1152 + r + 1) * 8);
        f16x8 xc0 = *(const f16x8*)(xh + ((size_t)bc * 1152 + r) * 8);
        f16x8 xc1 = *(const f16x8*)(xh + ((size_t)bc * 1152 + r + 1) * 8);
        f32x8 A0 = __builtin_convertvector(xa0, f32x8);
        f32x8 A1 = __builtin_convertvector(xa1, f32x8);
        f32x8 C0 = __builtin_convertvector(xc0, f32x8);
        f32x8 C1 = __builtin_convertvector(xc1, f32x8);
        float pa0 = A0[0]*W0[0] + A0[1]*W0[1] + A0[2]*W0[2] + A0[3]*W0[3]
                  + A0[4]*W0[4] + A0[5]*W0[5] + A0[6]*W0[6] + A0[7]*W0[7];
        float pa1 = A1[0]*W1[0] + A1[1]*W1[1] + A1[2]*W1[2] + A1[3]*W1[3]
                  + A1[4]*W1[4] + A1[5]*W1[5] + A1[6]*W1[6] + A1[7]*W1[7];
        float pc0 = C0[0]*W0[0] + C0[1]*W0[1] + C0[2]*W0[2] + C0[3]*W0[3]
                  + C0[4]*W0[4] + C0[5]*W0[5] + C0[6]*W0[6] + C0[7]*W0[7];
        float pc1 = C1[0]*W1[0] + C1[1]*W1[1] + C1[2]*W1[2] + C1[3]*W1[3]
                  + C1[4]*W1[4] + C1[5]*W1[5] + C1[6]*W1[6] + C1[7]*W1[7];
        f16* pba = pred + ((size_t)(c * 128 + ba) * 1152 + r) * 16 + o;
        f16* pbc = pred + ((size_t)(c * 128 + bc) * 1152 + r) * 16 + o;
        pba[0]  = (f16)pa0;  pba[16] = (f16)pa1;
        pbc[0]  = (f16)pc0;  pbc[16] = (f16)pc1;
        float psa = pa0 + pa1, psc = pc0 + pc1;
        psa += __shfl_xor(psa, 16); psc += __shfl_xor(psc, 16);
        psa += __shfl_xor(psa, 32); psc += __shfl_xor(psc, 32);
        if ((tid & 63) < 16) {
            atomicAdd(&s_sh[bb * 16 + o], psa);
            atomicAdd(&s_sh[(bb + 1) * 16 + o], psc);
        }
    }
    __syncthreads();
    for (int i = tid; i < 512; i += 256) {
        int bb = i >> 4, oo = i & 15;
        atomicAdd(&s0[((size_t)c * 128 + b0 + bb) * 16 + oo], s_sh[i]);
    }
}

// ---------------- routing iteration: lean pred stream, register-local o ----------------
__global__ __launch_bounds__(256) void route_f16v(
    const f16* __restrict__ pred,
    const float* __restrict__ sa, const float* __restrict__ za,
    const float* __restrict__ sb2, const float* __restrict__ zb2,
    float* __restrict__ s_out,      // [10,128,16]
    float* __restrict__ z_out)      // [10,128]
{
    const int c = blockIdx.x, b = blockIdx.y, tid = threadIdx.x;
    const size_t base = (size_t)(c * 128 + b) * 1152;
    const int o = tid & 15, seg = tid >> 4;

    __shared__ float lred[16][17];
    __shared__ float vs[16];

#define VSADD(S, Z) do {                                                      \
        float part_ = 0.f;                                                    \
        _Pragma("unroll")                                                     \
        for (int j = 0; j < 8; ++j) {                                         \
            int bb = seg * 8 + j;                                             \
            float zin = (Z) ? 1.f / (Z)[c * 128 + bb] : (1.f / 1152.f);       \
            float q = (S)[((size_t)c * 128 + bb) * 16 + o] * zin;             \
            part_ += q * q;                                                   \
        }                                                                     \
        lred[seg][o] = part_;                                                 \
        __syncthreads();                                                      \
        if (tid < 16) {                                                       \
            float t_ = 0.f;                                                   \
            _Pragma("unroll")                                                 \
            for (int i = 0; i < 16; ++i) t_ += lred[i][tid];                  \
            float zin = (Z) ? 1.f / (Z)[c * 128 + b] : (1.f / 1152.f);        \
            vs[tid] += (S)[((size_t)c * 128 + b) * 16 + tid] * zin *          \
                       sqrtf(t_) / (1.f + t_);                                \
        }                                                                     \
        __syncthreads();                                                      \
    } while (0)

    if (tid < 16) vs[tid] = 0.f;
    __syncthreads();
    VSADD(sa, za);
    if (sb2) VSADD(sb2, zb2);
#undef VSADD

    float vr[16];
#pragma unroll
    for (int j = 0; j < 16; ++j) vr[j] = vs[j];

    float sacc[16];
#pragma unroll
    for (int j = 0; j < 16; ++j) sacc[j] = 0.f;
    float zacc = 0.f;

    for (int r = tid; r < 1152; r += 256) {
        const f16x8* pp = (const f16x8*)(pred + (base + r) * 16);
        f32x8 q0 = __builtin_convertvector(pp[0], f32x8);
        f32x8 q1 = __builtin_convertvector(pp[1], f32x8);
        float t = 0.f;
#pragma unroll
        for (int j = 0; j < 8; ++j) t += q0[j] * vr[j] + q1[j] * vr[j + 8];
        float e = __expf(t);
#pragma unroll
        for (int j = 0; j < 8; ++j) { sacc[j] += e * q0[j]; sacc[j + 8] += e * q1[j]; }
        zacc += e;
    }

    __shared__ float red[256][16];
    __shared__ float red2[16][16];
    __shared__ float zred[256];
    __shared__ float zpart[16];
#pragma unroll
    for (int j = 0; j < 16; ++j) red[tid][j] = sacc[j];
    zred[tid] = zacc;
    __syncthreads();
    {
        float t = 0.f;
#pragma unroll
        for (int j = 0; j < 16; ++j) t += red[seg * 16 + j][o];
        red2[seg][o] = t;
        if (tid < 16) {
            float tz = 0.f;
#pragma unroll
            for (int j = 0; j < 16; ++j) tz += zred[tid * 16 + j];
            zpart[tid] = tz;
        }
    }
    __syncthreads();
    if (tid < 16) {
        float t = 0.f;
#pragma unroll
        for (int sg = 0; sg < 16; ++sg) t += red2[sg][tid];
        s_out[(size_t)(c * 128 + b) * 16 + tid] = t;
    } else if (tid == 16) {
        float tz = 0.f;
#pragma unroll
        for (int j = 0; j < 16; ++j) tz += zpart[j];
        z_out[c * 128 + b] = tz;
    }
}

// ---------------- final: v = squash(s/z, axis=batch) -> out[b,c,o] ----------------------
__global__ __launch_bounds__(128) void squash_final(
    const float* __restrict__ s, const float* __restrict__ z,
    float* __restrict__ out)
{
    const int c = blockIdx.x, b = threadIdx.x;   // 10 blocks, 128 threads
    float sv[16];
    const float* sp = s + ((size_t)c * 128 + b) * 16;
    float zin = 1.f / z[c * 128 + b];
#pragma unroll
    for (int o = 0; o < 16; ++o) sv[o] = sp[o] * zin;
    __shared__ float m[16][129];
#pragma unroll
    for (int o = 0; o < 16; ++o) m[o][b] = sv[o] * sv[o];
    __syncthreads();
    __shared__ float sn[16];
    if (b < 16) {
        float t = 0.f;
        for (int i = 0; i < 128; ++i) t += m[b][i];
        sn[b] = t;
    }
    __syncthreads();
#pragma unroll
    for (int o = 0; o < 16; ++o) {
        float scale = sqrtf(sn[o]) / (1.f + sn[o]);
        out[((size_t)b * 10 + c) * 16 + o] = sv[o] * scale;
    }
}

// ---------------- launch ----------------------------------------------------------------
extern "C" void kernel_launch(void* const* d_in, const int* in_sizes, int n_in,
                              void* d_out, int out_size, void* d_ws, size_t ws_size,
                              hipStream_t stream)
{
    (void)in_sizes; (void)n_in; (void)out_size; (void)ws_size;
    const float* inp = (const float*)d_in[0];
    const float* cw  = (const float*)d_in[1];
    const float* cb  = (const float*)d_in[2];
    const float* rw  = (const float*)d_in[3];
    float* out = (float*)d_out;

    // workspace layout (bytes), total ~75.4 MB:
    //   [0, 33.0M)        part f16 (conv -> combine); pred f16 [10,128,1152,16] (47.2 MB)
    //                     aliases [0,47.2M) AFTER combine (part + in_t prefix both dead)
    //   [33.0M, 59.2M)    in_t f16 (conv-time only)
    //   [59.2M, 69.9M)    w_t f16 (conv-time only)
    //   [69.9M, 72.8M)    rwh f16 [10,1152,16,8]
    //   [72.8M, 75.2M)    xh f16 [128,1152,8]
    //   [75.2M, 75.4M)    s0,sB,sC (3x81920) zB,zC (2x5120)
    char* ws = (char*)d_ws;
    f16*   part = (f16*)(ws);                       // 33,030,144
    f16*   pred = (f16*)(ws);                       // 47,185,920 (alias, post-combine)
    f16*   in_t = (f16*)(ws + 33030144);            // 26,214,400
    f16*   w_t  = (f16*)(ws + 59244544);            // 10,616,832 -> 69,861,376
    f16*   rwh  = (f16*)(ws + 69861376);            //  2,949,120 -> 72,810,496
    f16*   xh   = (f16*)(ws + 72810496);            //  2,359,296 -> 75,169,792
    float* s0   = (float*)(ws + 75169792);          //     81,920
    float* sB   = (float*)(ws + 75251712);          //     81,920
    float* sC   = (float*)(ws + 75333632);          //     81,920
    float* zB   = (float*)(ws + 75415552);          //      5,120
    float* zC   = (float*)(ws + 75420672);          //      5,120 -> 75,425,792

    // fused pre-pass: transpose + permute_w + permute_rw + zero(s0), one dispatch
    mega_pre<<<15028, 256, 0, stream>>>(inp, in_t, cw, w_t, rw, rwh, s0);

    conv_mfma<<<dim3(36, 1, SPLITK), 256, 0, stream>>>(in_t, w_t, part);
    combine_squash4<<<576, 256, 0, stream>>>(part, cb, xh);

    // pred materialized once (f16); iter-0 s fused into the pred pass
    pred_s0h<<<dim3(10, 36, 4), 256, 0, stream>>>(xh, rwh, pred, s0);

    // iters 1,2: lean pred streams, register-local o (telescoped logits: vs = v0(+v1))
    route_f16v<<<dim3(10, 128), 256, 0, stream>>>(pred, s0, nullptr, nullptr, nullptr,
                                                  sB, zB);                  // iter 1
    route_f16v<<<dim3(10, 128), 256, 0, stream>>>(pred, s0, nullptr, sB, zB,
                                                  sC, zC);                  // iter 2
    squash_final<<<10, 128, 0, stream>>>(sC, zC, out);
}

// Round 9
// 231.709 us; speedup vs baseline: 1.0924x; 1.0924x over previous
//
#include <hip/hip_runtime.h>
#include <math.h>

typedef _Float16 f16;
typedef _Float16 f16x4 __attribute__((ext_vector_type(4)));
typedef _Float16 f16x8 __attribute__((ext_vector_type(8)));
typedef float f32x4 __attribute__((ext_vector_type(4)));
typedef float f32x8 __attribute__((ext_vector_type(8)));

#define AS1 __attribute__((address_space(1)))
#define AS3 __attribute__((address_space(3)))

__device__ __forceinline__ void gld_lds16(const f16* g, f16* l) {
#if defined(__has_builtin) && __has_builtin(__builtin_amdgcn_global_load_lds)
    __builtin_amdgcn_global_load_lds((const AS1 void*)g, (AS3 void*)l, 16, 0, 0);
#else
    *(uint4*)l = *(const uint4*)g;
#endif
}

// ---------------- permute_w: conv_w [256][256][81] f32 -> w_t[n][p*256+cin] f16 ---------
// (own kernel: needs 41 KB LDS; fusing it into mega_pre2 would cap the transpose's
//  occupancy at ~3 blocks/CU — the R8 regression.)
__global__ __launch_bounds__(256) void permute_w(
    const float* __restrict__ cw, f16* __restrict__ w_t)
{
    const int n = blockIdx.x, t = threadIdx.x;
    __shared__ f16 buf[81 * 258];
    const float* src = cw + (size_t)n * 20736;
    for (int i = t; i < 20736; i += 256) {
        int cin = i / 81, p = i - cin * 81;
        buf[p * 258 + cin] = (f16)src[i];
    }
    __syncthreads();
    f16* dst = w_t + (size_t)n * 20736;
    for (int j = t; j < 20736; j += 256) {
        int p = j >> 8, cin = j & 255;
        dst[j] = buf[p * 258 + cin];
    }
}

// ---------------- fused small-smem pre-pass: transpose_input U permute_rw U zero-s0 -----
// blockIdx ranges: [0,13312) transpose (128x8x13), [13312,14752) permute_rw (1440),
// [14752,14772) zero s0 (20). 4.2 KB smem -> full occupancy for the transpose stream.
__global__ __launch_bounds__(256) void mega_pre2(
    const float* __restrict__ inp, f16* __restrict__ in_t,
    const float* __restrict__ rw,  f16* __restrict__ rwh,
    float* __restrict__ s0)
{
    __shared__ float t[32][33];
    const int bx = blockIdx.x, tid = threadIdx.x;

    if (bx < 13312) {
        // ---- transpose_input: [128,256,20,20] f32 -> [128,20,20,256] f16 ----
        const int b = bx & 127, c0 = ((bx >> 7) & 7) * 32, p0 = (bx >> 10) * 32;
        const int tx = tid & 31, ty = tid >> 5;            // 32 x 8
#pragma unroll
        for (int j = 0; j < 4; ++j) {
            int c = ty + j * 8, p = p0 + tx;
            if (p < 400) t[c][tx] = inp[((size_t)b * 256 + c0 + c) * 400 + p];
        }
        __syncthreads();
#pragma unroll
        for (int j = 0; j < 4; ++j) {
            int p = p0 + ty + j * 8;
            if (p < 400) in_t[((size_t)b * 400 + p) * 256 + c0 + tx] = (f16)t[tx][ty + j * 8];
        }
    } else if (bx < 14752) {
        // ---- permute_rw: rw [10,1152,8,16] f32 -> rwh [10,1152,16,8] f16 ----
        int g = (bx - 13312) * 256 + tid;                  // over 368640
        int cr = g >> 5, rem = g & 31;
        int o = rem >> 1, h = (rem & 1) * 4;
        const float* src = rw + (size_t)cr * 128 + o;
        f16x4 v;
#pragma unroll
        for (int j = 0; j < 4; ++j) v[j] = (f16)src[(h + j) * 16];
        *(f16x4*)(rwh + (size_t)cr * 128 + o * 8 + h) = v;
    } else {
        // ---- zero s0: 20480 floats = 5120 float4 ----
        int idx = (bx - 14752) * 256 + tid;
        ((float4*)s0)[idx] = make_float4(0.f, 0.f, 0.f, 0.f);
    }
}

// ---------------- conv as implicit-im2col MFMA GEMM, 2-phase interleaved pipeline ------
// (UNCHANGED — measured ~61 us, MfmaUtil ~33.)
#define SPLITK 14
__global__ __launch_bounds__(256, 2) void conv_mfma(
    const f16* __restrict__ in_t,   // [128,20,20,256]
    const f16* __restrict__ w_t,    // [256,20736]
    f16* __restrict__ part)         // [14,4608,256] f16
{
    __shared__ f16 As[3][128 * 32];
    __shared__ f16 Bs[3][256 * 32];
    const int tid = threadIdx.x;
    const int lane = tid & 63, wave = tid >> 6;
    const int wm = wave >> 1, wn = wave & 1;

    const int bid = blockIdx.x + 36 * blockIdx.z;
    const int wgid = (bid & 7) * 63 + (bid >> 3);
    const int m0 = (wgid % 36) * 128;
    const int kz = wgid / 36;

    const int kc0 = kz * 46 + (kz < 4 ? kz : 4);
    const int NT  = (kz < 4) ? 47 : 46;

    int srcA[2], srcB[4];
#pragma unroll
    for (int i = 0; i < 2; ++i) {
        int pairp = i * 32 + (tid >> 3);
        int chunk8 = (tid & 7) ^ (pairp & 7);
        int e = chunk8 >> 2, q4 = chunk8 & 3;
        int m = m0 + pairp * 2 + e;
        int b = m / 36, hw = m - b * 36;
        int ho = hw / 6, wo = hw - ho * 6;
        srcA[i] = ((b * 20 + 2 * ho) * 20 + 2 * wo) * 256 + q4 * 8;
    }
#pragma unroll
    for (int i = 0; i < 4; ++i) {
        int pairp = i * 32 + (tid >> 3);
        int chunk8 = (tid & 7) ^ (pairp & 7);
        int e = chunk8 >> 2, q4 = chunk8 & 3;
        int n = pairp * 2 + e;
        srcB[i] = n * 20736 + q4 * 8;
    }

    const int row = lane & 15, quad = lane >> 4;
    int offA[4], offB[8];
#pragma unroll
    for (int mt = 0; mt < 4; ++mt) {
        int m = wm * 64 + mt * 16 + row;
        int ph8 = (((m & 1) << 2) + quad) ^ ((m >> 1) & 7);
        offA[mt] = (m >> 1) * 64 + ph8 * 8;
    }
#pragma unroll
    for (int nt = 0; nt < 8; ++nt) {
        int n = wn * 128 + nt * 16 + row;
        int ph8 = (((n & 1) << 2) + quad) ^ ((n >> 1) & 7);
        offB[nt] = (n >> 1) * 64 + ph8 * 8;
    }

    f32x4 acc[4][8] = {};

#define KOFFS(T) int kc = kc0 + (T); int pp = kc >> 3, cq = kc & 7;           \
    int kh = pp / 9, kw = pp - kh * 9;                                        \
    int koffA = (kh * 20 + kw) * 256 + cq * 32; int koffB = kc * 32;
#define STAGE1(T, BUF) do { KOFFS(T)                                          \
        gld_lds16(in_t + srcA[0] + koffA, &As[BUF][tid * 8]);                 \
        gld_lds16(in_t + srcA[1] + koffA, &As[BUF][2048 + tid * 8]);          \
        gld_lds16(w_t + srcB[0] + koffB, &Bs[BUF][tid * 8]);                  \
    } while (0)
#define STAGE2(T, BUF) do { KOFFS(T)                                          \
        gld_lds16(w_t + srcB[1] + koffB, &Bs[BUF][2048 + tid * 8]);           \
        gld_lds16(w_t + srcB[2] + koffB, &Bs[BUF][4096 + tid * 8]);           \
        gld_lds16(w_t + srcB[3] + koffB, &Bs[BUF][6144 + tid * 8]);           \
    } while (0)

    STAGE1(0, 0); STAGE2(0, 0);
    STAGE1(1, 1); STAGE2(1, 1);
    asm volatile("s_waitcnt vmcnt(6)" ::: "memory");
    __builtin_amdgcn_s_barrier();

    int buf = 0;
    for (int t = 0; t < NT; ++t) {
        const f16* Ab = &As[buf][0];
        const f16* Bb = &Bs[buf][0];
        int bn = buf + 2; if (bn >= 3) bn -= 3;
        f16x8 af[4], bfr[8];

        // ---------------- phase A: af[0..3], bfr[0..3] -> acc[*][0..3] ----------------
#pragma unroll
        for (int mt = 0; mt < 4; ++mt) af[mt] = *(const f16x8*)(Ab + offA[mt]);
#pragma unroll
        for (int nt = 0; nt < 4; ++nt) bfr[nt] = *(const f16x8*)(Bb + offB[nt]);
        if (t + 2 < NT) STAGE1(t + 2, bn);
        __builtin_amdgcn_s_barrier();
        asm volatile("s_waitcnt lgkmcnt(0)" ::: "memory");
        __builtin_amdgcn_sched_barrier(0);
        __builtin_amdgcn_s_setprio(1);
#pragma unroll
        for (int mt = 0; mt < 4; ++mt)
#pragma unroll
            for (int nt = 0; nt < 4; ++nt)
                acc[mt][nt] = __builtin_amdgcn_mfma_f32_16x16x32_f16(
                    af[mt], bfr[nt], acc[mt][nt], 0, 0, 0);
        __builtin_amdgcn_s_setprio(0);
        __builtin_amdgcn_s_barrier();

        // ---------------- phase B: bfr[4..7] -> acc[*][4..7] --------------------------
#pragma unroll
        for (int nt = 4; nt < 8; ++nt) bfr[nt] = *(const f16x8*)(Bb + offB[nt]);
        if (t + 2 < NT) STAGE2(t + 2, bn);
        if (t + 2 < NT)
            asm volatile("s_waitcnt vmcnt(6)" ::: "memory");
        else if (t + 1 < NT)
            asm volatile("s_waitcnt vmcnt(0)" ::: "memory");
        __builtin_amdgcn_s_barrier();
        asm volatile("s_waitcnt lgkmcnt(0)" ::: "memory");
        __builtin_amdgcn_sched_barrier(0);
        __builtin_amdgcn_s_setprio(1);
#pragma unroll
        for (int mt = 0; mt < 4; ++mt)
#pragma unroll
            for (int nt = 4; nt < 8; ++nt)
                acc[mt][nt] = __builtin_amdgcn_mfma_f32_16x16x32_f16(
                    af[mt], bfr[nt], acc[mt][nt], 0, 0, 0);
        __builtin_amdgcn_s_setprio(0);
        __builtin_amdgcn_s_barrier();

        if (++buf == 3) buf = 0;
    }
#undef STAGE1
#undef STAGE2
#undef KOFFS

    const int col = lane & 15, qr = (lane >> 4) * 4;
    f16* pb = part + (size_t)kz * 4608 * 256;
#pragma unroll
    for (int mt = 0; mt < 4; ++mt)
#pragma unroll
        for (int rg = 0; rg < 4; ++rg) {
            int m = m0 + wm * 64 + mt * 16 + qr + rg;
#pragma unroll
            for (int nt = 0; nt < 8; ++nt) {
                int n = wn * 128 + nt * 16 + col;
                pb[(size_t)m * 256 + n] = (f16)acc[mt][nt][rg];
            }
        }
}

// ---------------- split-K reduce + bias + capsule squash -> xh[128,1152,8] f16 ----------
// (R7 version — byte-identical.)
__global__ __launch_bounds__(256) void combine_squash(
    const f16* __restrict__ part, const float* __restrict__ bias,
    f16* __restrict__ xh)
{
    int idx = blockIdx.x * 256 + threadIdx.x;   // over 4608*8
    int m = idx >> 3, g = idx & 7;              // g: group of 4 o's
    int b = m / 36, hw = m - b * 36;
    float val[8][4];
#pragma unroll
    for (int k = 0; k < 8; ++k)
#pragma unroll
        for (int j = 0; j < 4; ++j) val[k][j] = bias[k * 32 + g * 4 + j];
#pragma unroll
    for (int s = 0; s < SPLITK; ++s) {
        const f16* p = part + ((size_t)s * 4608 + m) * 256 + g * 4;
#pragma unroll
        for (int k = 0; k < 8; ++k) {
            f16x4 v = *(const f16x4*)(p + k * 32);
#pragma unroll
            for (int j = 0; j < 4; ++j) val[k][j] += (float)v[j];
        }
    }
#pragma unroll
    for (int j = 0; j < 4; ++j) {
        float sn = 0.f;
#pragma unroll
        for (int k = 0; k < 8; ++k) sn += val[k][j] * val[k][j];
        float scale = sqrtf(sn) / (1.f + sn);
        int r = (g * 4 + j) * 36 + hw;
        f16x8 hv;
#pragma unroll
        for (int k = 0; k < 8; ++k) hv[k] = (f16)(val[k][j] * scale);
        *(f16x8*)(xh + ((size_t)b * 1152 + r) * 8) = hv;
    }
}

// ---------------- pred (f16, materialized) + fused routing-iter-0 s-accumulation --------
// (R7 version — byte-identical.)
__global__ __launch_bounds__(256) void pred_s0h(
    const f16* __restrict__ xh,     // [128,1152,8]
    const f16* __restrict__ rwh,    // [10,1152,16,8]
    f16* __restrict__ pred,         // [10,128,1152,16]
    float* __restrict__ s0)         // [10,128,16] pre-zeroed
{
    const int c = blockIdx.x, r0 = blockIdx.y * 32, b0 = blockIdx.z * 32;
    const int tid = threadIdx.x;
    const int o = tid & 15, rp = tid >> 4;
    const int r = r0 + rp * 2;

    __shared__ float s_sh[32 * 16];
    s_sh[tid] = 0.f; s_sh[tid + 256] = 0.f;

    f16x8 w0h = *(const f16x8*)(rwh + ((size_t)(c * 1152 + r) * 16 + o) * 8);
    f16x8 w1h = *(const f16x8*)(rwh + ((size_t)(c * 1152 + r + 1) * 16 + o) * 8);
    f32x8 W0 = __builtin_convertvector(w0h, f32x8);
    f32x8 W1 = __builtin_convertvector(w1h, f32x8);
    __syncthreads();

    for (int bb = 0; bb < 32; ++bb) {
        const int b = b0 + bb;
        f16x8 x0h = *(const f16x8*)(xh + ((size_t)b * 1152 + r) * 8);
        f16x8 x1h = *(const f16x8*)(xh + ((size_t)b * 1152 + r + 1) * 8);
        f32x8 X0 = __builtin_convertvector(x0h, f32x8);
        f32x8 X1 = __builtin_convertvector(x1h, f32x8);
        float p0 = X0[0]*W0[0] + X0[1]*W0[1] + X0[2]*W0[2] + X0[3]*W0[3]
                 + X0[4]*W0[4] + X0[5]*W0[5] + X0[6]*W0[6] + X0[7]*W0[7];
        float p1 = X1[0]*W1[0] + X1[1]*W1[1] + X1[2]*W1[2] + X1[3]*W1[3]
                 + X1[4]*W1[4] + X1[5]*W1[5] + X1[6]*W1[6] + X1[7]*W1[7];
        f16* pb = pred + ((size_t)(c * 128 + b) * 1152 + r) * 16 + o;
        pb[0]  = (f16)p0;
        pb[16] = (f16)p1;
        // iter-0 accumulation: sum over this block's 32 routes
        float ps = p0 + p1;
        ps += __shfl_xor(ps, 16);
        ps += __shfl_xor(ps, 32);           // lanes 0-15: sum over wave's 4 r-pairs
        if ((tid & 63) < 16) atomicAdd(&s_sh[bb * 16 + o], ps);
    }
    __syncthreads();
    for (int i = tid; i < 512; i += 256) {
        int bb = i >> 4, oo = i & 15;
        atomicAdd(&s0[((size_t)c * 128 + b0 + bb) * 16 + oo], s_sh[i]);
    }
}

// ---------------- routing iteration: lean pred stream, register-local o ----------------
// (R7 version — byte-identical.)
__global__ __launch_bounds__(256) void route_f16v(
    const f16* __restrict__ pred,
    const float* __restrict__ sa, const float* __restrict__ za,
    const float* __restrict__ sb2, const float* __restrict__ zb2,
    float* __restrict__ s_out,      // [10,128,16]
    float* __restrict__ z_out)      // [10,128]
{
    const int c = blockIdx.x, b = blockIdx.y, tid = threadIdx.x;
    const size_t base = (size_t)(c * 128 + b) * 1152;
    const int o = tid & 15, seg = tid >> 4;

    __shared__ float lred[16][17];
    __shared__ float vs[16];

#define VSADD(S, Z) do {                                                      \
        float part_ = 0.f;                                                    \
        _Pragma("unroll")                                                     \
        for (int j = 0; j < 8; ++j) {                                         \
            int bb = seg * 8 + j;                                             \
            float zin = (Z) ? 1.f / (Z)[c * 128 + bb] : (1.f / 1152.f);       \
            float q = (S)[((size_t)c * 128 + bb) * 16 + o] * zin;             \
            part_ += q * q;                                                   \
        }                                                                     \
        lred[seg][o] = part_;                                                 \
        __syncthreads();                                                      \
        if (tid < 16) {                                                       \
            float t_ = 0.f;                                                   \
            _Pragma("unroll")                                                 \
            for (int i = 0; i < 16; ++i) t_ += lred[i][tid];                  \
            float zin = (Z) ? 1.f / (Z)[c * 128 + b] : (1.f / 1152.f);        \
            vs[tid] += (S)[((size_t)c * 128 + b) * 16 + tid] * zin *          \
                       sqrtf(t_) / (1.f + t_);                                \
        }                                                                     \
        __syncthreads();                                                      \
    } while (0)

    if (tid < 16) vs[tid] = 0.f;
    __syncthreads();
    VSADD(sa, za);
    if (sb2) VSADD(sb2, zb2);
#undef VSADD

    float vr[16];
#pragma unroll
    for (int j = 0; j < 16; ++j) vr[j] = vs[j];

    float sacc[16];
#pragma unroll
    for (int j = 0; j < 16; ++j) sacc[j] = 0.f;
    float zacc = 0.f;

    for (int r = tid; r < 1152; r += 256) {
        const f16x8* pp = (const f16x8*)(pred + (base + r) * 16);
        f32x8 q0 = __builtin_convertvector(pp[0], f32x8);
        f32x8 q1 = __builtin_convertvector(pp[1], f32x8);
        float t = 0.f;
#pragma unroll
        for (int j = 0; j < 8; ++j) t += q0[j] * vr[j] + q1[j] * vr[j + 8];
        float e = __expf(t);
#pragma unroll
        for (int j = 0; j < 8; ++j) { sacc[j] += e * q0[j]; sacc[j + 8] += e * q1[j]; }
        zacc += e;
    }

    __shared__ float red[256][16];
    __shared__ float red2[16][16];
    __shared__ float zred[256];
    __shared__ float zpart[16];
#pragma unroll
    for (int j = 0; j < 16; ++j) red[tid][j] = sacc[j];
    zred[tid] = zacc;
    __syncthreads();
    {
        float t = 0.f;
#pragma unroll
        for (int j = 0; j < 16; ++j) t += red[seg * 16 + j][o];
        red2[seg][o] = t;
        if (tid < 16) {
            float tz = 0.f;
#pragma unroll
            for (int j = 0; j < 16; ++j) tz += zred[tid * 16 + j];
            zpart[tid] = tz;
        }
    }
    __syncthreads();
    if (tid < 16) {
        float t = 0.f;
#pragma unroll
        for (int sg = 0; sg < 16; ++sg) t += red2[sg][tid];
        s_out[(size_t)(c * 128 + b) * 16 + tid] = t;
    } else if (tid == 16) {
        float tz = 0.f;
#pragma unroll
        for (int j = 0; j < 16; ++j) tz += zpart[j];
        z_out[c * 128 + b] = tz;
    }
}

// ---------------- final: v = squash(s/z, axis=batch) -> out[b,c,o] ----------------------
__global__ __launch_bounds__(128) void squash_final(
    const float* __restrict__ s, const float* __restrict__ z,
    float* __restrict__ out)
{
    const int c = blockIdx.x, b = threadIdx.x;   // 10 blocks, 128 threads
    float sv[16];
    const float* sp = s + ((size_t)c * 128 + b) * 16;
    float zin = 1.f / z[c * 128 + b];
#pragma unroll
    for (int o = 0; o < 16; ++o) sv[o] = sp[o] * zin;
    __shared__ float m[16][129];
#pragma unroll
    for (int o = 0; o < 16; ++o) m[o][b] = sv[o] * sv[o];
    __syncthreads();
    __shared__ float sn[16];
    if (b < 16) {
        float t = 0.f;
        for (int i = 0; i < 128; ++i) t += m[b][i];
        sn[b] = t;
    }
    __syncthreads();
#pragma unroll
    for (int o = 0; o < 16; ++o) {
        float scale = sqrtf(sn[o]) / (1.f + sn[o]);
        out[((size_t)b * 10 + c) * 16 + o] = sv[o] * scale;
    }
}

// ---------------- launch ----------------------------------------------------------------
extern "C" void kernel_launch(void* const* d_in, const int* in_sizes, int n_in,
                              void* d_out, int out_size, void* d_ws, size_t ws_size,
                              hipStream_t stream)
{
    (void)in_sizes; (void)n_in; (void)out_size; (void)ws_size;
    const float* inp = (const float*)d_in[0];
    const float* cw  = (const float*)d_in[1];
    const float* cb  = (const float*)d_in[2];
    const float* rw  = (const float*)d_in[3];
    float* out = (float*)d_out;

    // workspace layout (bytes), total ~75.4 MB:
    //   [0, 33.0M)        part f16 (conv -> combine); pred f16 [10,128,1152,16] (47.2 MB)
    //                     aliases [0,47.2M) AFTER combine (part + in_t prefix both dead)
    //   [33.0M, 59.2M)    in_t f16 (conv-time only)
    //   [59.2M, 69.9M)    w_t f16 (conv-time only)
    //   [69.9M, 72.8M)    rwh f16 [10,1152,16,8]
    //   [72.8M, 75.2M)    xh f16 [128,1152,8]
    //   [75.2M, 75.4M)    s0,sB,sC (3x81920) zB,zC (2x5120)
    char* ws = (char*)d_ws;
    f16*   part = (f16*)(ws);                       // 33,030,144
    f16*   pred = (f16*)(ws);                       // 47,185,920 (alias, post-combine)
    f16*   in_t = (f16*)(ws + 33030144);            // 26,214,400
    f16*   w_t  = (f16*)(ws + 59244544);            // 10,616,832 -> 69,861,376
    f16*   rwh  = (f16*)(ws + 69861376);            //  2,949,120 -> 72,810,496
    f16*   xh   = (f16*)(ws + 72810496);            //  2,359,296 -> 75,169,792
    float* s0   = (float*)(ws + 75169792);          //     81,920
    float* sB   = (float*)(ws + 75251712);          //     81,920
    float* sC   = (float*)(ws + 75333632);          //     81,920
    float* zB   = (float*)(ws + 75415552);          //      5,120
    float* zC   = (float*)(ws + 75420672);          //      5,120 -> 75,425,792

    // pre-passes: permute_w first (41 KB smem, 256 blocks), then the fused
    // small-smem stream (transpose + permute_rw + zero-s0) — 2 dispatches total.
    permute_w<<<256, 256, 0, stream>>>(cw, w_t);
    mega_pre2<<<14772, 256, 0, stream>>>(inp, in_t, rw, rwh, s0);

    conv_mfma<<<dim3(36, 1, SPLITK), 256, 0, stream>>>(in_t, w_t, part);
    combine_squash<<<144, 256, 0, stream>>>(part, cb, xh);

    // pred materialized once (f16); iter-0 s fused into the pred pass
    pred_s0h<<<dim3(10, 36, 4), 256, 0, stream>>>(xh, rwh, pred, s0);

    // iters 1,2: lean pred streams, register-local o (telescoped logits: vs = v0(+v1))
    route_f16v<<<dim3(10, 128), 256, 0, stream>>>(pred, s0, nullptr, nullptr, nullptr,
                                                  sB, zB);                  // iter 1
    route_f16v<<<dim3(10, 128), 256, 0, stream>>>(pred, s0, nullptr, sB, zB,
                                                  sC, zC);                  // iter 2
    squash_final<<<10, 128, 0, stream>>>(sC, zC, out);
}